// Round 1
// baseline (45.409 us; speedup 1.0000x reference)
//
#include <hip/hip_runtime.h>
#include <stdint.h>

#define BTOT 8192
#define NSS  4096
#define LL   64
#define BT   32          // batches per workgroup
#define STT  32          // states per tile
#define NT   (NSS/STT)   // 128 state tiles
#define JROWB 80         // padded LDS row bytes for J tile (32 states * 2B + 16 pad)

typedef __bf16 bf16x8 __attribute__((ext_vector_type(8)));
typedef float  f32x4  __attribute__((ext_vector_type(4)));

static __device__ __forceinline__ unsigned short f2bf(float x){
  union { float f; uint32_t u; } v; v.f = x;
  uint32_t r = v.u + 0x7fffu + ((v.u >> 16) & 1u);
  return (unsigned short)(r >> 16);
}
static __device__ __forceinline__ float bf2f(unsigned short b){
  union { uint32_t u; float f; } v; v.u = ((uint32_t)b) << 16; return v.f;
}

// Build S in bf16 (row-major [NS][64]) and S^T in bf16 ([64][NS]) in workspace.
__global__ void prepack_kernel(const float* __restrict__ S,
                               unsigned short* __restrict__ Sb,
                               unsigned short* __restrict__ STb){
  int i = blockIdx.x * blockDim.x + threadIdx.x;   // grid covers NS*L exactly
  Sb[i] = f2bf(S[i]);                               // coalesced read+write
  int l = i >> 12;                                  // i = l*4096 + s
  int s = i & (NSS - 1);
  STb[i] = f2bf(S[s * LL + l]);                     // coalesced write, strided read (L2-hot)
}

__launch_bounds__(256, 1)
__global__ void fused_kernel(const float* __restrict__ f,
                             const float* __restrict__ y,
                             const float* __restrict__ mask,
                             const unsigned short* __restrict__ Sb,
                             const unsigned short* __restrict__ STb,
                             float* __restrict__ out,      // [1 + BTOT*LL]
                             float* __restrict__ parts){   // [gridDim.x]
  const int tid  = threadIdx.x;
  const int w    = tid >> 6;       // wave id 0..3
  const int lane = tid & 63;
  const int c16  = lane & 15;
  const int q4   = lane >> 4;      // 0..3
  const int bb   = blockIdx.x * BT;

  __shared__ unsigned char jraw[4][32 * JROWB];  // per-wave J tile [32 batches][32 states bf16]
  __shared__ float nred[4][LL * 33];             // per-wave num partials, stride 33 to kill conflicts
  __shared__ float zred[4][128];                 // [w][q4*32 + b]
  __shared__ float zfin[BT];
  __shared__ float wred[4];

  // ---- prologue: f B-fragments with hi/lo bf16 split (register-resident all loop) ----
  // B-frag layout for mfma_f32_16x16x32_bf16: col = lane&15 (batch), k = (lane>>4)*8 + j (label)
  bf16x8 fhi[2][2], flo[2][2];
  #pragma unroll
  for (int g = 0; g < 2; ++g){
    const float* frow = f + (size_t)(bb + g*16 + c16) * LL;
    #pragma unroll
    for (int kc = 0; kc < 2; ++kc){
      float vv[8];
      *(float4*)&vv[0] = *(const float4*)&frow[kc*32 + 8*q4];
      *(float4*)&vv[4] = *(const float4*)&frow[kc*32 + 8*q4 + 4];
      union { unsigned short u[8]; bf16x8 v; } H, Lo;
      #pragma unroll
      for (int j = 0; j < 8; ++j){
        unsigned short h = f2bf(vv[j]);
        H.u[j]  = h;
        Lo.u[j] = f2bf(vv[j] - bf2f(h));
      }
      fhi[g][kc] = H.v; flo[g][kc] = Lo.v;
    }
  }

  f32x4 acc2[4][2];   // num accumulators: [label-tile][batch-group]
  #pragma unroll
  for (int lt = 0; lt < 4; ++lt)
    #pragma unroll
    for (int g = 0; g < 2; ++g) acc2[lt][g] = (f32x4){0.f,0.f,0.f,0.f};
  float zpart[2] = {0.f, 0.f};

  unsigned char* jb = jraw[w];

  // ---- main loop: each wave owns a disjoint set of state tiles; no barriers ----
  for (int t = w; t < NT; t += 4){
    const int sbase = t * STT;

    // GEMM1: potential[s_tile, b_tile] = S @ f^T   (A = S rows, exact in bf16)
    // A-frag: row = lane&15 (state), k = (lane>>4)*8+j (label) -> contiguous 16B
    bf16x8 a1[2][2];
    #pragma unroll
    for (int ss = 0; ss < 2; ++ss)
      #pragma unroll
      for (int kc = 0; kc < 2; ++kc)
        a1[ss][kc] = *(const bf16x8*)&Sb[(size_t)(sbase + ss*16 + c16)*LL + kc*32 + 8*q4];

    f32x4 acc1[2][2];
    #pragma unroll
    for (int ss = 0; ss < 2; ++ss)
      #pragma unroll
      for (int g = 0; g < 2; ++g){
        f32x4 a = (f32x4){0.f,0.f,0.f,0.f};
        #pragma unroll
        for (int kc = 0; kc < 2; ++kc){
          a = __builtin_amdgcn_mfma_f32_16x16x32_bf16(a1[ss][kc], fhi[g][kc], a, 0,0,0);
          a = __builtin_amdgcn_mfma_f32_16x16x32_bf16(a1[ss][kc], flo[g][kc], a, 0,0,0);
        }
        acc1[ss][g] = a;
      }

    // exp -> z partial -> pack bf16 -> LDS (transposed: [batch row][state col])
    // D-layout: col = lane&15 (batch), row = (lane>>4)*4 + jj (state within 16)
    #pragma unroll
    for (int ss = 0; ss < 2; ++ss)
      #pragma unroll
      for (int g = 0; g < 2; ++g){
        float J0 = __expf(acc1[ss][g][0]);
        float J1 = __expf(acc1[ss][g][1]);
        float J2 = __expf(acc1[ss][g][2]);
        float J3 = __expf(acc1[ss][g][3]);
        zpart[g] += (J0 + J1) + (J2 + J3);
        uint32_t w0 = (uint32_t)f2bf(J0) | ((uint32_t)f2bf(J1) << 16);
        uint32_t w1 = (uint32_t)f2bf(J2) | ((uint32_t)f2bf(J3) << 16);
        int row = g*16 + c16;
        *(uint2*)&jb[row*JROWB + ss*32 + q4*8] = make_uint2(w0, w1);
      }

    // GEMM2: num[l, b] += S^T @ J ; B-frag of J: col = batch, k = 8*q4+j states -> 16B LDS read
    bf16x8 b2[2];
    #pragma unroll
    for (int g = 0; g < 2; ++g){
      int row = g*16 + c16;
      b2[g] = *(const bf16x8*)&jb[row*JROWB + q4*16];
    }
    #pragma unroll
    for (int lt = 0; lt < 4; ++lt){
      bf16x8 a2 = *(const bf16x8*)&STb[(size_t)(lt*16 + c16)*NSS + sbase + 8*q4];
      #pragma unroll
      for (int g = 0; g < 2; ++g)
        acc2[lt][g] = __builtin_amdgcn_mfma_f32_16x16x32_bf16(a2, b2[g], acc2[lt][g], 0,0,0);
    }
  }

  // ---- epilogue: cross-wave reduce num and z, compute pMargin + BCE ----
  __syncthreads();
  #pragma unroll
  for (int lt = 0; lt < 4; ++lt)
    #pragma unroll
    for (int g = 0; g < 2; ++g)
      #pragma unroll
      for (int jj = 0; jj < 4; ++jj){
        int l = lt*16 + q4*4 + jj;     // D row = label
        int b = g*16 + c16;            // D col = batch
        nred[w][l*33 + b] = acc2[lt][g][jj];
      }
  zred[w][q4*32 + c16]      = zpart[0];
  zred[w][q4*32 + 16 + c16] = zpart[1];
  __syncthreads();

  if (tid < BT){
    float z = 0.f;
    #pragma unroll
    for (int ww = 0; ww < 4; ++ww)
      #pragma unroll
      for (int qq = 0; qq < 4; ++qq) z += zred[ww][qq*32 + tid];
    zfin[tid] = z;
  }
  __syncthreads();

  float lsum = 0.f;
  #pragma unroll
  for (int it = 0; it < 8; ++it){
    int idx = it*256 + tid;
    int b = idx >> 6, l = idx & 63;
    float num = (nred[0][l*33+b] + nred[1][l*33+b]) + (nred[2][l*33+b] + nred[3][l*33+b]);
    float p = num / zfin[b];
    p = fminf(p, 1.0f);
    size_t gi = (size_t)(bb + b)*LL + l;
    out[1 + gi] = p;
    float lg = fmaxf(__logf(p), -100.f);
    float l1 = fmaxf(log1pf(-p), -100.f);
    float yv = y[gi], mv = mask[gi];
    lsum += -(yv*lg + (1.f - yv)*l1) * mv;
  }
  #pragma unroll
  for (int off = 32; off; off >>= 1) lsum += __shfl_down(lsum, off);
  if (lane == 0) wred[w] = lsum;
  __syncthreads();
  if (tid == 0) parts[blockIdx.x] = (wred[0] + wred[1]) + (wred[2] + wred[3]);
}

__global__ void loss_kernel(const float* __restrict__ parts, float* __restrict__ out){
  float v = parts[threadIdx.x];            // 256 partials, one per WG
  #pragma unroll
  for (int off = 32; off; off >>= 1) v += __shfl_down(v, off);
  __shared__ float sred[4];
  int w = threadIdx.x >> 6, lane = threadIdx.x & 63;
  if (lane == 0) sred[w] = v;
  __syncthreads();
  if (threadIdx.x == 0)
    out[0] = ((sred[0] + sred[1]) + (sred[2] + sred[3])) * (1.0f / ((float)BTOT * (float)LL));
}

extern "C" void kernel_launch(void* const* d_in, const int* in_sizes, int n_in,
                              void* d_out, int out_size, void* d_ws, size_t ws_size,
                              hipStream_t stream){
  const float* f = (const float*)d_in[0];
  const float* y = (const float*)d_in[1];
  const float* m = (const float*)d_in[2];
  const float* S = (const float*)d_in[3];
  float* out = (float*)d_out;

  unsigned short* Sb  = (unsigned short*)d_ws;                        // 512 KB
  unsigned short* STb = Sb + (size_t)NSS * LL;                        // 512 KB
  float* parts = (float*)((char*)d_ws + (size_t)2 * NSS * LL * sizeof(unsigned short));

  prepack_kernel<<<(NSS*LL)/256, 256, 0, stream>>>(S, Sb, STb);
  fused_kernel<<<BTOT/BT, 256, 0, stream>>>(f, y, m, Sb, STb, out, parts);
  loss_kernel<<<1, 256, 0, stream>>>(parts, out);
}